// Round 5
// baseline (131.975 us; speedup 1.0000x reference)
//
#include <hip/hip_runtime.h>
#include <hip/hip_bf16.h>

// NT-Xent loss: z1,z2 [4096,256] fp32 -> scalar loss.
// R8: epilogue-lite + doubled TLP. R7's VGPR=84 proved B-residency happened
// (AGPR-parked) yet per-tile cost stayed ~20k cy -> B latency was never the
// bottleneck. The invariants across R3-R7 are (a) the per-tile epilogue
// (32 exp + 16 shuffle-chains + ~18 contended atomics) and (b) ~15% occupancy
// (no TLP to hide ANY latency). Fixes:
//  - cross-tile row accumulation: rs[4][4] accumulates over the rt-run in
//    registers; flush (shuffles+atomics) once per run. Per-tile epilogue is
//    now 32 exp + 2 shuffle-pairs + 2 col atomics (always issued; zero
//    contribution on diag so the counted vmcnt stays exact).
//  - B panel split: first half issued before the exp block, second half after
//    it (exp VALU covers B2 latency); single s_waitcnt vmcnt(2) per tile.
//  - grid 256 -> 512 persistent blocks: 2 blocks/CU (LDS 128/160 KB), double
//    the resident waves.
// Kept: triangle symmetry, XOR-swizzled LDS A panel staged once per rt-run,
// opaque asm B loads, pair-dot in k_normalize.

#define TWO_N 8192
#define NPAIR 4096
#define DDIM  256
#define NT    64                    // 128-row tiles per dim
#define NBLK  (NT * (NT + 1) / 2)   // 2080 upper-triangle tiles
#define INV_T 2.0f
#define GEMM_GRID 512               // persistent blocks, 2 per CU

typedef __attribute__((ext_vector_type(8))) short bf16x8;
typedef __attribute__((ext_vector_type(4))) float f32x4;

typedef __attribute__((address_space(1))) void gvoid_t;
typedef __attribute__((address_space(3))) void lvoid_t;

__device__ __forceinline__ void gload_lds16(const void* g, void* l) {
    __builtin_amdgcn_global_load_lds((gvoid_t*)g, (lvoid_t*)l, 16, 0, 0);
}

// ---------------- Kernel 1: normalize + quantize + pair-dot + zero scratch --
// grid 1024 x 256: one wave per PAIR i (handles rows i and i+4096).
__global__ void k_normalize(const float* __restrict__ z1,
                            const float* __restrict__ z2,
                            __hip_bfloat16* __restrict__ zn,
                            float* __restrict__ e_diag,
                            float* __restrict__ pos,
                            float* __restrict__ row_sumexp,
                            float* __restrict__ out) {
    if (threadIdx.x < 8) row_sumexp[blockIdx.x * 8 + threadIdx.x] = 0.0f;
    if (blockIdx.x == 0 && threadIdx.x == 0) out[0] = 0.0f;

    const int w    = threadIdx.x >> 6;
    const int lane = threadIdx.x & 63;
    const int i    = blockIdx.x * 4 + w;

    float4 a = ((const float4*)(z1 + (size_t)i * DDIM))[lane];
    float4 b = ((const float4*)(z2 + (size_t)i * DDIM))[lane];

    float s1 = a.x * a.x + a.y * a.y + a.z * a.z + a.w * a.w;
    float s2 = b.x * b.x + b.y * b.y + b.z * b.z + b.w * b.w;
    float dd = a.x * b.x + a.y * b.y + a.z * b.z + a.w * b.w;
#pragma unroll
    for (int m = 1; m < 64; m <<= 1) {
        s1 += __shfl_xor(s1, m, 64);
        s2 += __shfl_xor(s2, m, 64);
        dd += __shfl_xor(dd, m, 64);
    }

    float inv1 = 1.0f / fmaxf(sqrtf(s1), 1e-8f);   // matches reference eps
    float inv2 = 1.0f / fmaxf(sqrtf(s2), 1e-8f);

    __hip_bfloat16 q1[4], q2[4];
    q1[0] = __float2bfloat16(a.x * inv1); q1[1] = __float2bfloat16(a.y * inv1);
    q1[2] = __float2bfloat16(a.z * inv1); q1[3] = __float2bfloat16(a.w * inv1);
    q2[0] = __float2bfloat16(b.x * inv2); q2[1] = __float2bfloat16(b.y * inv2);
    q2[2] = __float2bfloat16(b.z * inv2); q2[3] = __float2bfloat16(b.w * inv2);

    float qs1 = 0.0f, qs2 = 0.0f;
#pragma unroll
    for (int j = 0; j < 4; ++j) {
        float f1 = __bfloat162float(q1[j]);
        float f2 = __bfloat162float(q2[j]);
        qs1 += f1 * f1;
        qs2 += f2 * f2;
    }
#pragma unroll
    for (int m = 1; m < 64; m <<= 1) {
        qs1 += __shfl_xor(qs1, m, 64);
        qs2 += __shfl_xor(qs2, m, 64);
    }

    *reinterpret_cast<uint2*>(zn + (size_t)i * DDIM + lane * 4) =
        *reinterpret_cast<uint2*>(q1);
    *reinterpret_cast<uint2*>(zn + (size_t)(i + NPAIR) * DDIM + lane * 4) =
        *reinterpret_cast<uint2*>(q2);

    if (lane == 0) {
        e_diag[i]         = __expf(qs1 * INV_T);   // matches GEMM's bf16 self-dot
        e_diag[i + NPAIR] = __expf(qs2 * INV_T);
        pos[i]            = dd * inv1 * inv2 * INV_T;  // positive-pair term, pure fp32
    }
}

// ---------------- Kernel 2: persistent symmetric MFMA self-GEMM + sums ------
// 512 persistent blocks x 512 threads (8 waves, 2x4 over the 128x128 tile).
// Each block processes tiles [bid*2080/512, (bid+1)*2080/512) rt-major.
__global__ __launch_bounds__(512, 2)
void k_gemm_sumexp(const __hip_bfloat16* __restrict__ zn,
                   float* __restrict__ row_sumexp) {
    __shared__ __align__(128) __hip_bfloat16 Asmem[128 * DDIM];   // 64 KB

    const int tid  = threadIdx.x;
    const int lane = tid & 63;
    const int w    = tid >> 6;
    const int wr   = w >> 2;          // 0/1: rows wr*64..+64
    const int wc   = w & 3;           // 0..3: cols wc*32..+32
    const int lr   = lane & 15;
    const int quad = lane >> 4;

    const int t0 = (int)(((long)blockIdx.x * NBLK) >> 9);
    const int t1 = (int)(((long)(blockIdx.x + 1) * NBLK) >> 9);

    // --- decode t0 -> (rt, ct); then advance incrementally (rt-major) ---
    int b = t0;
    int rt = (int)(64.5f - sqrtf(64.5f * 64.5f - 2.0f * (float)b));
    if (rt < 0) rt = 0;
    if (rt > NT - 1) rt = NT - 1;
    while (rt > 0 && NT * rt - (rt * (rt - 1)) / 2 > b) --rt;
    while (NT * (rt + 1) - ((rt + 1) * rt) / 2 <= b) ++rt;
    int ct = rt + (b - (NT * rt - (rt * (rt - 1)) / 2));

    // --- A fragment LDS byte offsets (swizzled; tile-invariant) ---
    int pa[4];
#pragma unroll
    for (int mi = 0; mi < 4; ++mi)
        pa[mi] = (wr * 64 + mi * 16 + lr) * (DDIM * 2) + ((quad ^ (lr & 7)) << 4);

    int cur_rt = -1;
    f32x4 acc[4][2];
    float rs[4][4];
#pragma unroll
    for (int mi = 0; mi < 4; ++mi)
#pragma unroll
        for (int r = 0; r < 4; ++r) rs[mi][r] = 0.0f;
    int  pCol = 0;
    bool pDiag = false, havePrev = false;

    // exp + accumulate prev tile's acc into rs (rows) and cs (cols). VALU only.
    auto epi_accum = [&](float& cs0, float& cs1) {
#pragma unroll
        for (int mi = 0; mi < 4; ++mi)
#pragma unroll
            for (int r = 0; r < 4; ++r) {
                float e0 = __expf(acc[mi][0][r] * INV_T);
                float e1 = __expf(acc[mi][1][r] * INV_T);
                rs[mi][r] += e0 + e1;
                cs0 += e0;
                cs1 += e1;
            }
    };
    // col-sum reduce + 2 atomics (ALWAYS issued: zero contribution on diag,
    // so the non-restage path's vmcnt(2) count is exact every tile).
    auto epi_cols = [&](float cs0, float cs1) {
        if (pDiag) { cs0 = 0.0f; cs1 = 0.0f; }
        cs0 += __shfl_xor(cs0, 16, 64); cs0 += __shfl_xor(cs0, 32, 64);
        cs1 += __shfl_xor(cs1, 16, 64); cs1 += __shfl_xor(cs1, 32, 64);
        if (quad == 0) {
            atomicAdd(&row_sumexp[pCol + wc * 32 + lr], cs0);
            atomicAdd(&row_sumexp[pCol + wc * 32 + 16 + lr], cs1);
        }
    };
    // flush the run's accumulated row sums; once per rt-run.
    auto flush_rows = [&](int rowb) {
#pragma unroll
        for (int mi = 0; mi < 4; ++mi)
#pragma unroll
            for (int r = 0; r < 4; ++r) {
                float v = rs[mi][r];
                v += __shfl_xor(v, 1, 64);
                v += __shfl_xor(v, 2, 64);
                v += __shfl_xor(v, 4, 64);
                v += __shfl_xor(v, 8, 64);
                if (lr == 0)
                    atomicAdd(&row_sumexp[rowb + wr * 64 + mi * 16 + quad * 4 + r], v);
                rs[mi][r] = 0.0f;
            }
    };

    for (int t = t0; t < t1; ++t) {
        const int  row_base = rt * 128;
        const int  col_base = ct * 128;
        const bool diag     = (rt == ct);
        const bool restage  = (rt != cur_rt);    // block-uniform

        const __hip_bfloat16* gB0 =
            zn + (size_t)(col_base + wc * 32 + lr) * DDIM + quad * 8;
        bf16x8 Bfr[8][2];

        if (restage) {
            // finish the previous run completely before touching the A panel
            if (havePrev) { float c0 = 0.f, c1 = 0.f; epi_accum(c0, c1); epi_cols(c0, c1); }
            if (cur_rt >= 0) flush_rows(cur_rt * 128);
            __syncthreads();   // all waves done reading old A
            // stage A(rt): 512 thr x 8 rounds x 16B; row j*16+(tid>>5),
            // chunk slot c'=tid&31, source ck = (c'&24)|((c'&7)^(row&7)).
            const int ck = (tid & 24) | ((tid & 7) ^ ((tid >> 5) & 7));
            const char* gA = (const char*)(zn + (size_t)row_base * DDIM)
                           + (tid >> 5) * (DDIM * 2) + ck * 16;
            char* lA = (char*)Asmem + tid * 16;
#pragma unroll
            for (int j = 0; j < 8; ++j)
                gload_lds16(gA + (size_t)j * 16 * (DDIM * 2), lA + j * 8192);
            // full B panel for this tile
#pragma unroll
            for (int ks = 0; ks < 8; ++ks) {
                const __hip_bfloat16* p0 = gB0 + ks * 32;
                const __hip_bfloat16* p1 = p0 + 16 * DDIM;
                asm volatile("global_load_dwordx4 %0, %1, off"
                             : "=v"(Bfr[ks][0]) : "v"(p0) : "memory");
                asm volatile("global_load_dwordx4 %0, %1, off"
                             : "=v"(Bfr[ks][1]) : "v"(p1) : "memory");
            }
            cur_rt = rt;
            asm volatile("s_waitcnt vmcnt(0)" ::: "memory");   // drain A + B
            __syncthreads();                                    // A visible
        } else {
            // B first half (ks 0..3)
#pragma unroll
            for (int ks = 0; ks < 4; ++ks) {
                const __hip_bfloat16* p0 = gB0 + ks * 32;
                const __hip_bfloat16* p1 = p0 + 16 * DDIM;
                asm volatile("global_load_dwordx4 %0, %1, off"
                             : "=v"(Bfr[ks][0]) : "v"(p0) : "memory");
                asm volatile("global_load_dwordx4 %0, %1, off"
                             : "=v"(Bfr[ks][1]) : "v"(p1) : "memory");
            }
            // prev-tile exp/accumulate runs under B1 latency (VALU only)
            float c0 = 0.f, c1 = 0.f;
            epi_accum(c0, c1);
            // B second half (ks 4..7) — covered by the VALU above + cols below
#pragma unroll
            for (int ks = 4; ks < 8; ++ks) {
                const __hip_bfloat16* p0 = gB0 + ks * 32;
                const __hip_bfloat16* p1 = p0 + 16 * DDIM;
                asm volatile("global_load_dwordx4 %0, %1, off"
                             : "=v"(Bfr[ks][0]) : "v"(p0) : "memory");
                asm volatile("global_load_dwordx4 %0, %1, off"
                             : "=v"(Bfr[ks][1]) : "v"(p1) : "memory");
            }
            epi_cols(c0, c1);   // exactly 2 VMEM ops after the last B load
            asm volatile("s_waitcnt vmcnt(2)" ::: "memory");   // all 16 B done
        }
        __builtin_amdgcn_sched_barrier(0);   // rule #18: no MFMA hoisting

        pCol = col_base; pDiag = diag; havePrev = true;

#pragma unroll
        for (int mi = 0; mi < 4; ++mi)
#pragma unroll
            for (int ni = 0; ni < 2; ++ni)
                acc[mi][ni] = (f32x4){0.f, 0.f, 0.f, 0.f};

        bf16x8 afc[4];
#pragma unroll
        for (int mi = 0; mi < 4; ++mi)
            afc[mi] = *(const bf16x8*)((const char*)Asmem + pa[mi]);

        // --- pure LDS+register k-loop: zero global ops, zero barriers ---
#pragma unroll
        for (int kstep = 0; kstep < 8; ++kstep) {
            bf16x8 afn[4];
            if (kstep < 7) {
                const int kn   = kstep + 1;
                const int koff = (kn >> 1) << 7;
                const int kx   = (kn & 1) << 6;
#pragma unroll
                for (int mi = 0; mi < 4; ++mi)
                    afn[mi] = *(const bf16x8*)((const char*)Asmem + ((pa[mi] ^ kx) + koff));
            }
#pragma unroll
            for (int mi = 0; mi < 4; ++mi)
#pragma unroll
                for (int ni = 0; ni < 2; ++ni)
                    acc[mi][ni] = __builtin_amdgcn_mfma_f32_16x16x32_bf16(
                        afc[mi], Bfr[kstep][ni], acc[mi][ni], 0, 0, 0);
            if (kstep < 7) {
#pragma unroll
                for (int mi = 0; mi < 4; ++mi) afc[mi] = afn[mi];
            }
        }

        if (++ct >= NT) { ++rt; ct = rt; }   // advance in the triangle
    }

    // final tile's epilogue + final run flush
    { float c0 = 0.f, c1 = 0.f; epi_accum(c0, c1); epi_cols(c0, c1); }
    flush_rows(cur_rt * 128);
}

// ---------------- Kernel 3: tiny finisher ----------------
// grid 16 x 256: one thread per pair index.
__global__ void k_final(const float* __restrict__ row_sumexp,
                        const float* __restrict__ e_diag,
                        const float* __restrict__ pos,
                        float* __restrict__ out) {
    const int i    = blockIdx.x * 256 + threadIdx.x;   // 0..4095
    const int w    = threadIdx.x >> 6;
    const int lane = threadIdx.x & 63;

    float t = logf(row_sumexp[i] - e_diag[i])
            + logf(row_sumexp[i + NPAIR] - e_diag[i + NPAIR])
            - 2.0f * pos[i];
#pragma unroll
    for (int m = 1; m < 64; m <<= 1) t += __shfl_xor(t, m, 64);

    __shared__ float ps[4];
    if (lane == 0) ps[w] = t;
    __syncthreads();
    if (threadIdx.x == 0) {
        float s = (ps[0] + ps[1] + ps[2] + ps[3]) * (1.0f / (float)TWO_N);
        atomicAdd(out, s);
    }
}

extern "C" void kernel_launch(void* const* d_in, const int* in_sizes, int n_in,
                              void* d_out, int out_size, void* d_ws, size_t ws_size,
                              hipStream_t stream) {
    const float* z1 = (const float*)d_in[0];
    const float* z2 = (const float*)d_in[1];
    float* out = (float*)d_out;

    char* ws = (char*)d_ws;
    __hip_bfloat16* zn  = (__hip_bfloat16*)ws;                       // 4 MB
    float* row_sumexp   = (float*)(ws + (size_t)TWO_N * DDIM * 2);   // 32 KB
    float* e_diag       = row_sumexp + TWO_N;                        // 32 KB
    float* pos          = e_diag + TWO_N;                            // 16 KB

    k_normalize<<<NPAIR / 4, 256, 0, stream>>>(z1, z2, zn, e_diag, pos,
                                               row_sumexp, out);
    k_gemm_sumexp<<<GEMM_GRID, 512, 0, stream>>>(zn, row_sumexp);
    k_final<<<NPAIR / 256, 256, 0, stream>>>(row_sumexp, e_diag, pos, out);
}